// Round 14
// baseline (1458.495 us; speedup 1.0000x reference)
//
#include <hip/hip_runtime.h>
#include <math.h>

typedef __attribute__((ext_vector_type(8))) short short8;
typedef __attribute__((ext_vector_type(4))) float f32x4;

#define EPI_QKV   0
#define EPI_PEXP  1
#define EPI_R     2
#define EPI_Z     3
#define EPI_N     4

__device__ __forceinline__ unsigned short f2bf(float f) {
    unsigned int u = __float_as_uint(f);
    u += 0x7fffu + ((u >> 16) & 1u);
    return (unsigned short)(u >> 16);
}
__device__ __forceinline__ float bf2f(unsigned short s) {
    return __uint_as_float(((unsigned int)s) << 16);
}

struct alignas(8) us4 { unsigned short a, b, c, d; };

#define GLD_LDS16(gp, lp) \
    __builtin_amdgcn_global_load_lds((const __attribute__((address_space(1))) unsigned int*)(gp), \
                                     (__attribute__((address_space(3))) unsigned int*)(lp), 16, 0, 0)

#define BAR   do { asm volatile("" ::: "memory"); __builtin_amdgcn_s_barrier(); \
                   asm volatile("" ::: "memory"); } while (0)
#define VMC0  asm volatile("s_waitcnt vmcnt(0)" ::: "memory")

// ============================================================================
// 128x256 tile, BK=32, 512 threads (8 waves: 2M x 4N, wave tile 64x64),
// __launch_bounds__(512,4) -> VGPR<=128 -> TWO BLOCKS PER CU (the round-13
// diagnosis: 1 block/CU serializes LDS-read and MFMA pipes; a second
// resident block provides the overlap no intra-block schedule could).
// LDS 48 KiB: A[2][128][32] + B[2][256][32] bf16, LINEAR layout (row stride
// 64 B is bank-balanced for ds_read_b128: 8 accesses/bank = 1-KB minimum;
// no swizzle needed at BK=32).
// Single-barrier K-tile loop (round-9-proven hazards):
//   { stage tile t+1 -> q (3 gload_lds); read a[4],b[4] from p (8 ds_b128);
//     16 MFMA (each acc written once); VMC0; BAR }
// WAR: q's previous readers finished their ds_reads before their MFMA issue,
// which precedes the prior BAR; stage(q) comes after it. RAW: VMC0 before
// BAR, reads after. Acc deps: one update per acc per tile (distance 16).
// ============================================================================
template<int EPI, int SWZ>
__global__ void __launch_bounds__(512, 4)
gemm128(const unsigned short* __restrict__ A, long long sAb, int lda,
        const unsigned short* __restrict__ Bt, long long sBb, int ldb,
        const float* __restrict__ bias,
        void* __restrict__ C, long long sCb, int ldc,
        int K, float scale,
        const float* __restrict__ hptr,
        const unsigned short* __restrict__ updptr,
        float* __restrict__ psum,
        unsigned short* __restrict__ vt)
{
    extern __shared__ char smem[];   // 49152 B

    const int z = blockIdx.z;
    A  += (size_t)z * (size_t)sAb;
    Bt += (size_t)z * (size_t)sBb;

    int bx, by;
    if (SWZ) {
        // grid (8,256): keep one XCD on 32 contiguous row-panels (all 8 cols)
        const int bid = blockIdx.y * 8 + blockIdx.x;
        const int xcd = bid & 7, i = bid >> 3;      // i: 0..255
        bx = i & 7;
        by = (xcd << 5) + (i >> 3);
    } else {
        bx = blockIdx.x; by = blockIdx.y;
    }
    const int m0 = by * 128;
    const int n0 = bx * 256;

    const int tid = threadIdx.x;
    const int w  = tid >> 6;      // wave 0..7
    const int l  = tid & 63;
    const int wr = w >> 2;        // 0..1 (M half: 64 rows)
    const int wc = w & 3;         // 0..3 (N quarter: 64 cols)
    const int lr = l & 15;
    const int lg = l >> 4;

    const long long ldab = (long long)lda * 2;
    const long long ldbb = (long long)ldb * 2;

    f32x4 acc[4][4] = {};
    short8 a[4], b[4];

#define AOFF(buf) ((buf) * 8192)
#define BOFF(buf) (16384 + (buf) * 16384)

// stage A tile (128x32): 1 gload/thread; row=tid>>2, colb=(tid&3)*16; dest linear tid*16
#define SA(buf, base) { \
    const char* g_ = (const char*)(base) + (size_t)(m0 + (tid >> 2)) * ldab + ((tid & 3) << 4); \
    GLD_LDS16(g_, smem + AOFF(buf) + ((w << 10) + (l << 4))); }

// stage B tile (256x32): 2 gloads/thread
#define SB(buf, base) { \
    _Pragma("unroll") \
    for (int j = 0; j < 2; ++j) { \
        const char* g_ = (const char*)(base) + \
            (size_t)(n0 + j * 128 + (tid >> 2)) * ldbb + ((tid & 3) << 4); \
        GLD_LDS16(g_, smem + BOFF(buf) + j * 8192 + ((w << 10) + (l << 4))); } }

#define LDA4(buf) { \
    const char* Ab_ = smem + AOFF(buf); \
    _Pragma("unroll") \
    for (int mf = 0; mf < 4; ++mf) \
        a[mf] = *(const short8*)(Ab_ + (wr * 64 + mf * 16 + lr) * 64 + lg * 16); }

#define LDB4(buf) { \
    const char* Bb_ = smem + BOFF(buf); \
    _Pragma("unroll") \
    for (int nf = 0; nf < 4; ++nf) \
        b[nf] = *(const short8*)(Bb_ + (wc * 64 + nf * 16 + lr) * 64 + lg * 16); }

#define MMA16() { \
    __builtin_amdgcn_s_setprio(1); \
    _Pragma("unroll") \
    for (int mf = 0; mf < 4; ++mf) \
    _Pragma("unroll") \
    for (int nf = 0; nf < 4; ++nf) \
        acc[mf][nf] = __builtin_amdgcn_mfma_f32_16x16x32_bf16( \
            a[mf], b[nf], acc[mf][nf], 0, 0, 0); \
    __builtin_amdgcn_s_setprio(0); }

    // prologue: tile0 -> buf0
    SA(0, A); SB(0, Bt);
    VMC0;
    BAR;

    const int NT = K >> 5;
    for (int t = 0; t < NT; ++t) {
        const int p = t & 1, q = p ^ 1;
        const bool s1 = (t + 1 < NT);
        const unsigned short* An = A  + (size_t)(t + 1) * 32;
        const unsigned short* Bn = Bt + (size_t)(t + 1) * 32;

        if (s1) { SA(q, An); SB(q, Bn); }   // 3 gload_lds (earliest issue)
        LDA4(p); LDB4(p);                   // 8 ds_read_b128
        MMA16();                            // 16 MFMA
        VMC0;                               // tile t+1 landed
        BAR;
    }

    // ======================= epilogues =======================
    const int Mb = gridDim.y << 7;          // rows per batch slab
    const size_t zc = (size_t)z * (size_t)sCb;

    if (EPI == EPI_PEXP) {
        float psl[4][4];
        #pragma unroll
        for (int mf = 0; mf < 4; ++mf)
            #pragma unroll
            for (int r = 0; r < 4; ++r) psl[mf][r] = 0.0f;

        #pragma unroll
        for (int mf = 0; mf < 4; ++mf)
        #pragma unroll
        for (int nf = 0; nf < 4; ++nf) {
            const int col = n0 + wc * 64 + nf * 16 + lr;
            #pragma unroll
            for (int r = 0; r < 4; ++r) {
                const int row = m0 + wr * 64 + mf * 16 + lg * 4 + r;
                const float e = __expf(acc[mf][nf][r] * scale);
                ((unsigned short*)C)[zc + (size_t)row * ldc + col] = f2bf(e);
                psl[mf][r] += e;
            }
        }
        #pragma unroll
        for (int d = 1; d < 16; d <<= 1)
            #pragma unroll
            for (int mf = 0; mf < 4; ++mf)
                #pragma unroll
                for (int r = 0; r < 4; ++r)
                    psl[mf][r] += __shfl_xor(psl[mf][r], d);
        __syncthreads();
        float* red = (float*)smem;             // [4 wc][128 rows] = 2 KB
        if (lr == 0) {
            #pragma unroll
            for (int mf = 0; mf < 4; ++mf)
                #pragma unroll
                for (int r = 0; r < 4; ++r)
                    red[wc * 128 + wr * 64 + mf * 16 + lg * 4 + r] = psl[mf][r];
        }
        __syncthreads();
        if (tid < 128) {
            const float sres = red[tid] + red[128 + tid] + red[256 + tid] + red[384 + tid];
            psum[(size_t)bx * 32768 + (size_t)z * 512 + m0 + tid] = sres;
        }
        return;
    }

    float invs[4][4];
    if (EPI == EPI_R || EPI == EPI_Z || EPI == EPI_N) {
        #pragma unroll
        for (int mf = 0; mf < 4; ++mf)
            #pragma unroll
            for (int r = 0; r < 4; ++r) {
                const int row = m0 + wr * 64 + mf * 16 + lg * 4 + r;
                const size_t gr = (size_t)z * 512 + row;
                invs[mf][r] = 1.0f / (psum[gr] + psum[32768 + gr]);
            }
    }

    #pragma unroll
    for (int mf = 0; mf < 4; ++mf) {
        #pragma unroll
        for (int nf = 0; nf < 4; ++nf) {
            const int col = n0 + wc * 64 + nf * 16 + lr;
            const float bval = (EPI == EPI_QKV) ? bias[col] : 0.0f;
            if (EPI == EPI_QKV && bx >= 4) {
                // direct V^T store: 4 consecutive channel-rows at fixed v-dim
                const int row0 = m0 + wr * 64 + mf * 16 + lg * 4;
                us4 o = { f2bf(acc[mf][nf][0] + bval),
                          f2bf(acc[mf][nf][1] + bval),
                          f2bf(acc[mf][nf][2] + bval),
                          f2bf(acc[mf][nf][3] + bval) };
                *(us4*)(vt + (size_t)(row0 >> 9) * 524288 +
                        (size_t)(col - 1024) * 512 + (row0 & 511)) = o;
            } else {
                #pragma unroll
                for (int r = 0; r < 4; ++r) {
                    const int row = m0 + wr * 64 + mf * 16 + lg * 4 + r;
                    float v = acc[mf][nf][r] + bval;
                    if (EPI == EPI_QKV) {
                        ((unsigned short*)C)[(size_t)row * ldc + col] = f2bf(v);
                    } else if (EPI == EPI_R) {
                        v *= invs[mf][r];
                        const size_t flat = (size_t)z * Mb + row;
                        const float hh = hptr[flat * 1024 + col];
                        const float sg = 1.0f / (1.0f + __expf(-v));
                        ((unsigned short*)C)[flat * 2048 + 1024 + col] = f2bf(hh * sg);
                    } else if (EPI == EPI_Z) {
                        v *= invs[mf][r];
                        const size_t flat = (size_t)z * Mb + row;
                        const float sg = 1.0f / (1.0f + __expf(-v));
                        ((unsigned short*)C)[flat * 1024 + col] = f2bf(sg);
                    } else { // EPI_N
                        v *= invs[mf][r];
                        const size_t flat = (size_t)z * Mb + row;
                        const float u  = bf2f(updptr[flat * 1024 + col]);
                        const float hh = hptr[flat * 1024 + col];
                        ((float*)C)[flat * 1024 + col] = (1.0f - u) * hh + u * tanhf(v);
                    }
                }
            }
        }
    }
#undef AOFF
#undef BOFF
#undef SA
#undef SB
#undef LDA4
#undef LDB4
#undef MMA16
}

// ============================================================================
// memory-bound helper kernels
// ============================================================================

__global__ void __launch_bounds__(256)
prep_xh(const float* __restrict__ x, const float* __restrict__ h, unsigned short* __restrict__ xh)
{
    const size_t t = (size_t)blockIdx.x * 256 + threadIdx.x;
    const size_t f = t * 4;
    const size_t row = f >> 10, col = f & 1023;
    const float4 vx = *(const float4*)(x + f);
    const float4 vh = *(const float4*)(h + f);
    us4 ox = { f2bf(vx.x), f2bf(vx.y), f2bf(vx.z), f2bf(vx.w) };
    us4 oh = { f2bf(vh.x), f2bf(vh.y), f2bf(vh.z), f2bf(vh.w) };
    *(us4*)(xh + row * 2048 + col)        = ox;
    *(us4*)(xh + row * 2048 + 1024 + col) = oh;
}

__global__ void __launch_bounds__(256)
transpose_w(const float* __restrict__ W, unsigned short* __restrict__ WT, int N)
{
    __shared__ float t[32][33];
    const int k0 = blockIdx.y * 32, n0 = blockIdx.x * 32;
    const int tx = threadIdx.x & 31, ty = threadIdx.x >> 5;
    #pragma unroll
    for (int i = 0; i < 4; ++i)
        t[ty + i * 8][tx] = W[(size_t)(k0 + ty + i * 8) * N + n0 + tx];
    __syncthreads();
    #pragma unroll
    for (int i = 0; i < 4; ++i)
        WT[(size_t)(n0 + ty + i * 8) * 2048 + k0 + tx] = f2bf(t[tx][ty + i * 8]);
}

__global__ void __launch_bounds__(256)
layernorm1024(float* __restrict__ Y, const float* __restrict__ gamma, const float* __restrict__ beta)
{
    const int row = blockIdx.x * 4 + (threadIdx.x >> 6);
    const int l = threadIdx.x & 63;
    float* p = Y + (size_t)row * 1024;
    float4 v[4];
    float s = 0.0f, s2 = 0.0f;
    #pragma unroll
    for (int i = 0; i < 4; ++i) {
        v[i] = ((const float4*)p)[i * 64 + l];
        s  += v[i].x + v[i].y + v[i].z + v[i].w;
        s2 += v[i].x * v[i].x + v[i].y * v[i].y + v[i].z * v[i].z + v[i].w * v[i].w;
    }
    #pragma unroll
    for (int d = 32; d; d >>= 1) { s += __shfl_xor(s, d); s2 += __shfl_xor(s2, d); }
    const float mu = s * (1.0f / 1024.0f);
    const float var = s2 * (1.0f / 1024.0f) - mu * mu;
    const float inv = rsqrtf(var + 1e-5f);
    #pragma unroll
    for (int i = 0; i < 4; ++i) {
        const float4 gv = ((const float4*)gamma)[i * 64 + l];
        const float4 bv = ((const float4*)beta)[i * 64 + l];
        float4 o;
        o.x = (v[i].x - mu) * inv * gv.x + bv.x;
        o.y = (v[i].y - mu) * inv * gv.y + bv.y;
        o.z = (v[i].z - mu) * inv * gv.z + bv.z;
        o.w = (v[i].w - mu) * inv * gv.w + bv.w;
        ((float4*)p)[i * 64 + l] = o;
    }
}

__global__ void __launch_bounds__(256)
concat_bias(const float* __restrict__ a, const float* __restrict__ b,
            const float* __restrict__ c, float* __restrict__ o)
{
    const int i = blockIdx.x * 256 + threadIdx.x;
    o[i] = (i < 512) ? a[i] : (i < 1024) ? b[i - 512] : c[i - 1024];
}

extern "C" void kernel_launch(void* const* d_in, const int* in_sizes, int n_in,
                              void* d_out, int out_size, void* d_ws, size_t ws_size,
                              hipStream_t stream)
{
    (void)in_sizes; (void)n_in; (void)out_size; (void)ws_size;

    const float* x = (const float*)d_in[0];
    const float* h = (const float*)d_in[1];
    const float* Wf[9]; const float* bia[9];
    for (int g = 0; g < 3; ++g)
        for (int j = 0; j < 3; ++j) {
            Wf[g * 3 + j]  = (const float*)d_in[2 + g * 6 + j * 2];
            bia[g * 3 + j] = (const float*)d_in[2 + g * 6 + j * 2 + 1];
        }
    const float* gamma = (const float*)d_in[20];
    const float* beta  = (const float*)d_in[21];
    float* out = (float*)d_out;

    const int LDS_BYTES = 49152;
    hipFuncSetAttribute((const void*)gemm128<EPI_QKV, 1>,  hipFuncAttributeMaxDynamicSharedMemorySize, LDS_BYTES);
    hipFuncSetAttribute((const void*)gemm128<EPI_PEXP, 0>, hipFuncAttributeMaxDynamicSharedMemorySize, LDS_BYTES);
    hipFuncSetAttribute((const void*)gemm128<EPI_R, 0>,    hipFuncAttributeMaxDynamicSharedMemorySize, LDS_BYTES);
    hipFuncSetAttribute((const void*)gemm128<EPI_Z, 0>,    hipFuncAttributeMaxDynamicSharedMemorySize, LDS_BYTES);
    hipFuncSetAttribute((const void*)gemm128<EPI_N, 0>,    hipFuncAttributeMaxDynamicSharedMemorySize, LDS_BYTES);

    char* ws = (char*)d_ws;
    size_t off = 0;
    auto alloc = [&](size_t bytes) -> void* {
        void* p = ws + off; off += (bytes + 255) & ~(size_t)255; return p;
    };
    unsigned short* xh  = (unsigned short*)alloc((size_t)32768 * 2048 * 2); // 134 MB
    unsigned short* WT  = (unsigned short*)alloc((size_t)12582912 * 2);     // 24 MB
    unsigned short* QK  = (unsigned short*)alloc((size_t)32768 * 1024 * 2); // 67 MB
    unsigned short* Vt  = (unsigned short*)alloc((size_t)32768 * 1024 * 2); // 67 MB
    unsigned short* Pb  = (unsigned short*)alloc((size_t)64 * 512 * 512 * 2);// 33.5 MB
    unsigned short* upd = (unsigned short*)alloc((size_t)32768 * 1024 * 2); // 67 MB
    float*          psb = (float*)alloc((size_t)2 * 32768 * 4);             // 256 KB
    float*          bct = (float*)alloc((size_t)3 * 2048 * 4);

    size_t wtoff[9];
    {
        size_t o = 0;
        for (int g = 0; g < 3; ++g) {
            wtoff[g * 3 + 0] = o; o += (size_t)512 * 2048;
            wtoff[g * 3 + 1] = o; o += (size_t)512 * 2048;
            wtoff[g * 3 + 2] = o; o += (size_t)1024 * 2048;
        }
    }

    prep_xh<<<32768, 256, 0, stream>>>(x, h, xh);
    for (int i = 0; i < 9; ++i) {
        const int N = (i % 3 == 2) ? 1024 : 512;
        transpose_w<<<dim3(N / 32, 64, 1), 256, 0, stream>>>(Wf[i], WT + wtoff[i], N);
    }
    for (int g = 0; g < 3; ++g)
        concat_bias<<<8, 256, 0, stream>>>(bia[g * 3 + 0], bia[g * 3 + 1], bia[g * 3 + 2], bct + g * 2048);

    const float scscale = 0.044194173824159216f; // 1/sqrt(512)

    auto gate = [&](int g, int epi) {
        const unsigned short* wT = WT + wtoff[g * 3 + 0];
        // fused QKV projection (N=2048): Q,K -> QK buffer; V -> Vt (transposed store)
        gemm128<EPI_QKV, 1><<<dim3(8, 256, 1), 512, LDS_BYTES, stream>>>(
            xh, 0, 2048, wT, 0, 2048, bct + g * 2048,
            QK, 0, 1024, 2048, 0.0f, nullptr, nullptr, nullptr, Vt);
        // P~ = exp(Q@K^T * scale) + per-row partial sums (batched over 64)
        gemm128<EPI_PEXP, 0><<<dim3(2, 4, 64), 512, LDS_BYTES, stream>>>(
            QK, 524288, 1024, QK + 512, 524288, 1024, nullptr,
            Pb, 262144, 512, 512, scscale, nullptr, nullptr, psb, nullptr);
        // PV (batched), rowsum-normalized, fused gate epilogue
        if (epi == EPI_Z)
            gemm128<EPI_Z, 0><<<dim3(4, 4, 64), 512, LDS_BYTES, stream>>>(
                Pb, 262144, 512, Vt, 524288, 512, nullptr,
                upd, 0, 1024, 512, 0.0f, nullptr, nullptr, psb, nullptr);
        else if (epi == EPI_R)
            gemm128<EPI_R, 0><<<dim3(4, 4, 64), 512, LDS_BYTES, stream>>>(
                Pb, 262144, 512, Vt, 524288, 512, nullptr,
                xh, 0, 2048, 512, 0.0f, h, nullptr, psb, nullptr);
        else
            gemm128<EPI_N, 0><<<dim3(4, 4, 64), 512, LDS_BYTES, stream>>>(
                Pb, 262144, 512, Vt, 524288, 512, nullptr,
                out, 0, 1024, 512, 0.0f, h, upd, psb, nullptr);
    };

    gate(1, EPI_Z);  // update = sigmoid(z-attn)            (reads original xh)
    gate(0, EPI_R);  // xh[:,1024:] = bf16(h * sigmoid(r))  (in-place -> xhr)
    gate(2, EPI_N);  // out = (1-u)*h + u*tanh(n-attn)
    layernorm1024<<<8192, 256, 0, stream>>>(out, gamma, beta);
}